// Round 3
// baseline (351.274 us; speedup 1.0000x reference)
//
#include <hip/hip_runtime.h>
#include <stdint.h>

typedef unsigned short ushort_t;
typedef __attribute__((ext_vector_type(8))) short bf16x8;   // 8 bf16 = 4 VGPRs (MFMA A/B frag)
typedef __attribute__((ext_vector_type(4))) float f32x4;    // MFMA C/D frag / fp32 vec-load

#define BM 128
#define BN 128
#define BK 32
#define SCALING 2.0f

static __device__ __forceinline__ unsigned short f2b(float f) {
    union { float f; unsigned int i; } v;
    v.f = f;
    unsigned int r = 0x7FFFu + ((v.i >> 16) & 1u);   // round-to-nearest-even
    return (unsigned short)((v.i + r) >> 16);
}
static __device__ __forceinline__ unsigned int fbits(float f) {
    union { float f; unsigned int i; } v; v.f = f; return v.i;
}

// async global->LDS, 16 bytes/lane. HW dest = wave-uniform base + lane*16.
static __device__ __forceinline__ void ld_g2l16(const void* g, void* l) {
    __builtin_amdgcn_global_load_lds(
        (const __attribute__((address_space(1))) void*)g,
        (__attribute__((address_space(3))) void*)l,
        16, 0, 0);
}

// ---------------------------------------------------------------------------
// Kernel 1: W_eff[o][d] = W[o][d] + SCALING * sum_r B[o][r]*A[r][d]  (fp32 in, bf16 out RNE)
// ---------------------------------------------------------------------------
__global__ void weff_kernel(const float* __restrict__ W,
                            const float* __restrict__ A,
                            const float* __restrict__ Bm,
                            ushort_t* __restrict__ Weff,
                            int D, int R) {
    int gid = blockIdx.x * blockDim.x + threadIdx.x;   // one thread per 8 output elems
    int perRow = D >> 3;
    if (gid >= D * perRow) return;
    int o  = gid / perRow;
    int d0 = (gid - o * perRow) << 3;

    float br[16];
    for (int r = 0; r < R; ++r) br[r] = SCALING * Bm[(size_t)o * R + r];

    float acc[8];
    #pragma unroll
    for (int j = 0; j < 8; ++j) acc[j] = W[(size_t)o * D + d0 + j];
    for (int r = 0; r < R; ++r) {
        #pragma unroll
        for (int j = 0; j < 8; ++j) acc[j] += br[r] * A[(size_t)r * D + d0 + j];
    }
    union { bf16x8 v; unsigned short s[8]; } ov;
    #pragma unroll
    for (int j = 0; j < 8; ++j) ov.s[j] = f2b(acc[j]);
    *(bf16x8*)(Weff + (size_t)o * D + d0) = ov.v;
}

// ---------------------------------------------------------------------------
// Kernel 2: Y[m][n] = sum_k X[m][k]*Wt[n][k] + bias[n]
//   X fp32 (converted to bf16 in-kernel, v_perm truncation), Wt bf16, Y fp32.
//   128x128 tile, BK=32, 4 waves of 64x64, 16x16x32 MFMA, global_load_lds,
//   XOR-swizzled LDS (conflict-free frag reads), XCD-aware block remap.
// ---------------------------------------------------------------------------
__global__ __launch_bounds__(256) void gemm_xf32_bt_bias(
    const float*    __restrict__ X,     // [M,K] fp32
    const ushort_t* __restrict__ Wt,    // [N,K] bf16
    const float*    __restrict__ bias,  // [N]   fp32
    float*          __restrict__ Y,     // [M,N] fp32
    int M, int N, int K)
{
    __shared__ __align__(16) float    sA[BM * BK];   // 16 KB, 16B-chunk slot = c ^ (m&7)
    __shared__ __align__(16) ushort_t sB[BN * BK];   //  8 KB, 16B-chunk slot = c ^ ((m>>1)&3)

    const int tid  = threadIdx.x;
    const int lane = tid & 63;

    // ---- XCD-aware tile assignment: each XCD gets 32 M-tiles x all N-tiles ----
    const int nT = N / BN;                   // 8
    const int mT = M / BM;                   // 256
    int mTile, nTile;
    if (((mT * nT) & 7) == 0 && ((mT * nT) >> 3) % nT == 0) {
        const int xcd = blockIdx.x & 7;
        const int loc = blockIdx.x >> 3;
        const int mPerXcd = ((mT * nT) >> 3) / nT;   // 32
        mTile = xcd * mPerXcd + loc / nT;
        nTile = loc % nT;
    } else {
        nTile = blockIdx.x % nT;
        mTile = blockIdx.x / nT;
    }
    const int mBase = mTile * BM;
    const int nBase = nTile * BN;

    const int wave  = tid >> 6;
    const int waveM = (wave & 1) * 64;
    const int waveN = (wave >> 1) * 64;

    // ---- staging addresses (swizzle folded into the GLOBAL source address) ----
    // A (fp32): LDS slot s=tid&7 of row tid>>3 holds k-chunk c = s ^ (row&7)
    const int aChunk = (tid & 7) ^ ((tid >> 3) & 7);
    const float* gA = X + (size_t)(mBase + (tid >> 3)) * K + aChunk * 4;
    float* lA = sA + tid * 4;                       // byte off tid*16
    // B (bf16): LDS slot s=tid&3 of row tid>>2 holds k-chunk c = s ^ ((row>>1)&3)
    const int bChunk = (tid & 3) ^ ((tid >> 3) & 3);
    const ushort_t* gB = Wt + (size_t)(nBase + (tid >> 2)) * K + bChunk * 8;
    ushort_t* lB = sB + tid * 8;                    // byte off tid*16

    const int fRow = lane & 15;
    const int g    = lane >> 4;                     // k-group: fK = g*8

    f32x4 acc[4][4];
    #pragma unroll
    for (int i = 0; i < 4; ++i)
        #pragma unroll
        for (int j = 0; j < 4; ++j)
            acc[i][j] = (f32x4){0.f, 0.f, 0.f, 0.f};

    for (int k0 = 0; k0 < K; k0 += BK) {
        __syncthreads();
        ld_g2l16(gA + k0,                  lA);          // A rows  0-31
        ld_g2l16(gA + k0 + (size_t)32 * K, lA + 1024);   // A rows 32-63
        ld_g2l16(gA + k0 + (size_t)64 * K, lA + 2048);   // A rows 64-95
        ld_g2l16(gA + k0 + (size_t)96 * K, lA + 3072);   // A rows 96-127
        ld_g2l16(gB + k0,                  lB);          // B rows  0-63
        ld_g2l16(gB + k0 + (size_t)64 * K, lB + 2048);   // B rows 64-127
        __syncthreads();

        bf16x8 aF[4], bF[4];
        #pragma unroll
        for (int i = 0; i < 4; ++i) {
            const int row = waveM + i * 16 + fRow;
            const float* base = sA + row * 32;
            const int r7 = row & 7;
            f32x4 lo = *(const f32x4*)(base + (((2 * g)     ^ r7) * 4));
            f32x4 hi = *(const f32x4*)(base + (((2 * g + 1) ^ r7) * 4));
            union { bf16x8 v; unsigned int d[4]; } u;
            u.d[0] = __builtin_amdgcn_perm(fbits(lo[1]), fbits(lo[0]), 0x07060302u);
            u.d[1] = __builtin_amdgcn_perm(fbits(lo[3]), fbits(lo[2]), 0x07060302u);
            u.d[2] = __builtin_amdgcn_perm(fbits(hi[1]), fbits(hi[0]), 0x07060302u);
            u.d[3] = __builtin_amdgcn_perm(fbits(hi[3]), fbits(hi[2]), 0x07060302u);
            aF[i] = u.v;
        }
        #pragma unroll
        for (int j = 0; j < 4; ++j) {
            const int row = waveN + j * 16 + fRow;
            const int slot = g ^ ((row >> 1) & 3);
            bF[j] = *(const bf16x8*)(sB + row * 32 + slot * 8);
        }

        #pragma unroll
        for (int i = 0; i < 4; ++i)
            #pragma unroll
            for (int j = 0; j < 4; ++j)
                acc[i][j] = __builtin_amdgcn_mfma_f32_16x16x32_bf16(
                    aF[i], bF[j], acc[i][j], 0, 0, 0);
    }

    // epilogue: C/D layout col(n)=lane&15, row(m)=(lane>>4)*4+reg
    const int col  = lane & 15;
    const int rowq = (lane >> 4) * 4;
    #pragma unroll
    for (int j = 0; j < 4; ++j) {
        const int n    = nBase + waveN + j * 16 + col;
        const float bv = bias[n];
        #pragma unroll
        for (int i = 0; i < 4; ++i) {
            const int mRow = mBase + waveM + i * 16 + rowq;
            #pragma unroll
            for (int r = 0; r < 4; ++r)
                Y[(size_t)(mRow + r) * N + n] = acc[i][j][r] + bv;
        }
    }
}

// ---------------------------------------------------------------------------
// Fallback (only if ws too small): correct fused fp32 vector kernel.
// ---------------------------------------------------------------------------
__global__ __launch_bounds__(256) void fused_naive(
    const float* __restrict__ x, const float* __restrict__ W,
    const float* __restrict__ b, const float* __restrict__ A,
    const float* __restrict__ Bm, float* __restrict__ y, int D, int R)
{
    extern __shared__ float smem[];
    float* sx  = smem;
    float* red = smem + D;
    float* sh  = red + 256;
    const int tid = threadIdx.x;
    const int m   = blockIdx.x;

    for (int i = tid; i < D; i += 256) sx[i] = x[(size_t)m * D + i];
    __syncthreads();

    for (int r = 0; r < R; ++r) {
        float p = 0.f;
        for (int k = tid; k < D; k += 256) p += sx[k] * A[(size_t)r * D + k];
        red[tid] = p; __syncthreads();
        for (int s = 128; s > 0; s >>= 1) {
            if (tid < s) red[tid] += red[tid + s];
            __syncthreads();
        }
        if (tid == 0) sh[r] = red[0];
        __syncthreads();
    }

    for (int n = tid; n < D; n += 256) {
        float base = 0.f;
        const float* wr = W + (size_t)n * D;
        for (int k = 0; k < D; ++k) base += sx[k] * wr[k];
        float lora = 0.f;
        for (int r = 0; r < R; ++r) lora += sh[r] * Bm[(size_t)n * R + r];
        y[(size_t)m * D + n] = base + b[n] + SCALING * lora;
    }
}

extern "C" void kernel_launch(void* const* d_in, const int* in_sizes, int n_in,
                              void* d_out, int out_size, void* d_ws, size_t ws_size,
                              hipStream_t stream) {
    const float* x  = (const float*)d_in[0];
    const float* W  = (const float*)d_in[1];
    const float* b  = (const float*)d_in[2];
    const float* A  = (const float*)d_in[3];
    const float* Bm = (const float*)d_in[4];
    float* y = (float*)d_out;

    const int D = in_sizes[2];                 // 1024
    const int R = in_sizes[3] / D;             // 8
    const int M = in_sizes[0] / D;             // 32768

    const size_t weffBytes = (size_t)D * D * sizeof(ushort_t);   // 2 MB

    if (ws_size >= weffBytes && (D % BN) == 0 && (M % BM) == 0 && (D % BK) == 0) {
        ushort_t* Weff = (ushort_t*)d_ws;

        int wthreads = D * (D / 8);
        weff_kernel<<<dim3((wthreads + 255) / 256), 256, 0, stream>>>(W, A, Bm, Weff, D, R);

        dim3 grid((M / BM) * (D / BN));        // 1D; kernel does XCD-aware remap
        gemm_xf32_bt_bias<<<grid, 256, 0, stream>>>(x, Weff, b, y, M, D, D);
    } else {
        size_t shmem = (size_t)(D + 256 + R) * sizeof(float);
        fused_naive<<<dim3(M), 256, shmem, stream>>>(x, W, b, A, Bm, y, D, R);
    }
}

// Round 4
// 322.439 us; speedup vs baseline: 1.0894x; 1.0894x over previous
//
#include <hip/hip_runtime.h>
#include <stdint.h>

typedef unsigned short ushort_t;
typedef __attribute__((ext_vector_type(8))) short bf16x8;   // 8 bf16 = 4 VGPRs (MFMA A/B frag)
typedef __attribute__((ext_vector_type(4))) float f32x4;    // MFMA C/D frag / fp32 vec-load

#define BM 128
#define BN 128
#define BK 64
#define SCALING 2.0f

static __device__ __forceinline__ unsigned short f2b(float f) {
    union { float f; unsigned int i; } v;
    v.f = f;
    unsigned int r = 0x7FFFu + ((v.i >> 16) & 1u);   // round-to-nearest-even
    return (unsigned short)((v.i + r) >> 16);
}

// async global->LDS, 16 bytes/lane. HW dest = wave-uniform base + lane*16.
static __device__ __forceinline__ void ld_g2l16(const void* g, void* l) {
    __builtin_amdgcn_global_load_lds(
        (const __attribute__((address_space(1))) void*)g,
        (__attribute__((address_space(3))) void*)l,
        16, 0, 0);
}

// ---------------------------------------------------------------------------
// Kernel 1: W_eff[o][d] = W[o][d] + SCALING * sum_r B[o][r]*A[r][d]  (fp32 in, bf16 out RNE)
// ---------------------------------------------------------------------------
__global__ void weff_kernel(const float* __restrict__ W,
                            const float* __restrict__ A,
                            const float* __restrict__ Bm,
                            ushort_t* __restrict__ Weff,
                            int D, int R) {
    int gid = blockIdx.x * blockDim.x + threadIdx.x;
    int perRow = D >> 3;
    if (gid >= D * perRow) return;
    int o  = gid / perRow;
    int d0 = (gid - o * perRow) << 3;

    float br[16];
    for (int r = 0; r < R; ++r) br[r] = SCALING * Bm[(size_t)o * R + r];

    float acc[8];
    #pragma unroll
    for (int j = 0; j < 8; ++j) acc[j] = W[(size_t)o * D + d0 + j];
    for (int r = 0; r < R; ++r) {
        #pragma unroll
        for (int j = 0; j < 8; ++j) acc[j] += br[r] * A[(size_t)r * D + d0 + j];
    }
    union { bf16x8 v; unsigned short s[8]; } ov;
    #pragma unroll
    for (int j = 0; j < 8; ++j) ov.s[j] = f2b(acc[j]);
    *(bf16x8*)(Weff + (size_t)o * D + d0) = ov.v;
}

// ---------------------------------------------------------------------------
// Kernel 2: x fp32 -> bf16 RNE (8 elems/thread)
// ---------------------------------------------------------------------------
__global__ void cvt_x_kernel(const float* __restrict__ x, ushort_t* __restrict__ xb, long n) {
    long gid = (long)(blockIdx.x * blockDim.x + threadIdx.x) * 8;
    if (gid >= n) return;
    f32x4 a = *(const f32x4*)(x + gid);
    f32x4 b = *(const f32x4*)(x + gid + 4);
    union { bf16x8 v; unsigned short s[8]; } ov;
    ov.s[0] = f2b(a[0]); ov.s[1] = f2b(a[1]); ov.s[2] = f2b(a[2]); ov.s[3] = f2b(a[3]);
    ov.s[4] = f2b(b[0]); ov.s[5] = f2b(b[1]); ov.s[6] = f2b(b[2]); ov.s[7] = f2b(b[3]);
    *(bf16x8*)(xb + gid) = ov.v;
}

// ---------------------------------------------------------------------------
// Kernel 3: Y[m][n] = sum_k X[m][k]*Wt[n][k] + bias[n]  (bf16 X/Wt, fp32 bias/out)
//   128x128 tile, BK=64 (16 barrier-drains instead of 32), 4 waves of 64x64,
//   16x16x32 MFMA x2 k-steps, global_load_lds 16B, XOR-swizzled LDS chunks
//   (row = 128B = 32 banks; swizzle spreads 16-lane groups over 8 bank-quads),
//   XCD-aware block remap (x slice + Weff stay in one XCD's L2/LLC path).
// ---------------------------------------------------------------------------
__global__ __launch_bounds__(256) void gemm_bt_bias(
    const ushort_t* __restrict__ X,     // [M,K] bf16
    const ushort_t* __restrict__ Wt,    // [N,K] bf16
    const float*    __restrict__ bias,  // [N]   fp32
    float*          __restrict__ Y,     // [M,N] fp32
    int M, int N, int K)
{
    __shared__ __align__(16) ushort_t sA[BM * BK];   // 16 KB; slot s of row r holds chunk s^(r&7)
    __shared__ __align__(16) ushort_t sB[BN * BK];   // 16 KB; same swizzle

    const int tid  = threadIdx.x;
    const int lane = tid & 63;

    // ---- XCD-aware tile assignment ----
    const int nT = N / BN;
    const int mT = M / BM;
    int mTile, nTile;
    if (((mT * nT) & 7) == 0 && (((mT * nT) >> 3) % nT) == 0) {
        const int xcd = blockIdx.x & 7;
        const int loc = blockIdx.x >> 3;
        const int mPerXcd = ((mT * nT) >> 3) / nT;
        mTile = xcd * mPerXcd + loc / nT;
        nTile = loc % nT;
    } else {
        nTile = blockIdx.x % nT;
        mTile = blockIdx.x / nT;
    }
    const int mBase = mTile * BM;
    const int nBase = nTile * BN;

    const int wave  = tid >> 6;
    const int waveM = (wave & 1) * 64;
    const int waveN = (wave >> 1) * 64;

    // ---- staging: row = tid>>3 (+32 per extra instr), slot = tid&7 holds chunk slot^(row&7)
    const int sRow   = tid >> 3;
    const int sChunk = (tid & 7) ^ (sRow & 7);       // row&7 invariant under +32
    const ushort_t* gA = X  + (size_t)(mBase + sRow) * K + sChunk * 8;
    const ushort_t* gB = Wt + (size_t)(nBase + sRow) * K + sChunk * 8;
    ushort_t* lA = sA + tid * 8;                     // byte offset tid*16 (HW-pinned order)
    ushort_t* lB = sB + tid * 8;

    const int fRow = lane & 15;
    const int g    = lane >> 4;

    f32x4 acc[4][4];
    #pragma unroll
    for (int i = 0; i < 4; ++i)
        #pragma unroll
        for (int j = 0; j < 4; ++j)
            acc[i][j] = (f32x4){0.f, 0.f, 0.f, 0.f};

    for (int k0 = 0; k0 < K; k0 += BK) {
        __syncthreads();
        #pragma unroll
        for (int q = 0; q < 4; ++q) {
            ld_g2l16(gA + k0 + (size_t)(q * 32) * K, lA + q * 2048);
            ld_g2l16(gB + k0 + (size_t)(q * 32) * K, lB + q * 2048);
        }
        __syncthreads();   // vmcnt(0) drain: tile visible

        #pragma unroll
        for (int ks = 0; ks < 2; ++ks) {
            bf16x8 aF[4], bF[4];
            #pragma unroll
            for (int i = 0; i < 4; ++i) {
                const int row  = waveM + i * 16 + fRow;
                const int slot = (ks * 4 + g) ^ (row & 7);
                aF[i] = *(const bf16x8*)(sA + row * BK + slot * 8);
            }
            #pragma unroll
            for (int j = 0; j < 4; ++j) {
                const int row  = waveN + j * 16 + fRow;
                const int slot = (ks * 4 + g) ^ (row & 7);
                bF[j] = *(const bf16x8*)(sB + row * BK + slot * 8);
            }
            #pragma unroll
            for (int i = 0; i < 4; ++i)
                #pragma unroll
                for (int j = 0; j < 4; ++j)
                    acc[i][j] = __builtin_amdgcn_mfma_f32_16x16x32_bf16(
                        aF[i], bF[j], acc[i][j], 0, 0, 0);
        }
    }

    // epilogue: C/D layout col(n)=lane&15, row(m)=(lane>>4)*4+reg
    const int col  = lane & 15;
    const int rowq = (lane >> 4) * 4;
    #pragma unroll
    for (int j = 0; j < 4; ++j) {
        const int n    = nBase + waveN + j * 16 + col;
        const float bv = bias[n];
        #pragma unroll
        for (int i = 0; i < 4; ++i) {
            const int mRow = mBase + waveM + i * 16 + rowq;
            #pragma unroll
            for (int r = 0; r < 4; ++r)
                Y[(size_t)(mRow + r) * N + n] = acc[i][j][r] + bv;
        }
    }
}

// ---------------------------------------------------------------------------
// Fallback (only if ws too small / shapes odd): correct fused fp32 kernel.
// ---------------------------------------------------------------------------
__global__ __launch_bounds__(256) void fused_naive(
    const float* __restrict__ x, const float* __restrict__ W,
    const float* __restrict__ b, const float* __restrict__ A,
    const float* __restrict__ Bm, float* __restrict__ y, int D, int R)
{
    extern __shared__ float smem[];
    float* sx  = smem;
    float* red = smem + D;
    float* sh  = red + 256;
    const int tid = threadIdx.x;
    const int m   = blockIdx.x;

    for (int i = tid; i < D; i += 256) sx[i] = x[(size_t)m * D + i];
    __syncthreads();

    for (int r = 0; r < R; ++r) {
        float p = 0.f;
        for (int k = tid; k < D; k += 256) p += sx[k] * A[(size_t)r * D + k];
        red[tid] = p; __syncthreads();
        for (int s = 128; s > 0; s >>= 1) {
            if (tid < s) red[tid] += red[tid + s];
            __syncthreads();
        }
        if (tid == 0) sh[r] = red[0];
        __syncthreads();
    }

    for (int n = tid; n < D; n += 256) {
        float base = 0.f;
        const float* wr = W + (size_t)n * D;
        for (int k = 0; k < D; ++k) base += sx[k] * wr[k];
        float lora = 0.f;
        for (int r = 0; r < R; ++r) lora += sh[r] * Bm[(size_t)n * R + r];
        y[(size_t)m * D + n] = base + b[n] + SCALING * lora;
    }
}

extern "C" void kernel_launch(void* const* d_in, const int* in_sizes, int n_in,
                              void* d_out, int out_size, void* d_ws, size_t ws_size,
                              hipStream_t stream) {
    const float* x  = (const float*)d_in[0];
    const float* W  = (const float*)d_in[1];
    const float* b  = (const float*)d_in[2];
    const float* A  = (const float*)d_in[3];
    const float* Bm = (const float*)d_in[4];
    float* y = (float*)d_out;

    const int D = in_sizes[2];                 // 1024
    const int R = in_sizes[3] / D;             // 8
    const int M = in_sizes[0] / D;             // 32768
    const long xN = (long)M * D;

    const size_t weffBytes = (size_t)D * D * sizeof(ushort_t);   // 2 MB
    const size_t xbBytes   = (size_t)xN * sizeof(ushort_t);      // 67 MB

    if (ws_size >= weffBytes + xbBytes &&
        (D % BN) == 0 && (M % BM) == 0 && (D % BK) == 0) {
        ushort_t* Weff = (ushort_t*)d_ws;
        ushort_t* xb   = (ushort_t*)((char*)d_ws + weffBytes);

        int wthreads = D * (D / 8);
        weff_kernel<<<dim3((wthreads + 255) / 256), 256, 0, stream>>>(W, A, Bm, Weff, D, R);

        long cthreads = xN / 8;
        cvt_x_kernel<<<dim3((unsigned)((cthreads + 255) / 256)), 256, 0, stream>>>(x, xb, xN);

        dim3 grid((M / BM) * (D / BN));        // 1D; kernel does XCD-aware remap
        gemm_bt_bias<<<grid, 256, 0, stream>>>(xb, Weff, b, y, M, D, D);
    } else {
        size_t shmem = (size_t)(D + 256 + R) * sizeof(float);
        fused_naive<<<dim3(M), 256, shmem, stream>>>(x, W, b, A, Bm, y, D, R);
    }
}